// Round 3
// baseline (142.588 us; speedup 1.0000x reference)
//
#include <hip/hip_runtime.h>
#include <math.h>

#define NG 2048
#define NPG 64
#define EPG 512
#define ETOT (NG*EPG)
#define IND 64
#define H1D 128
#define H2D 64
#define OUTD 2016

typedef __attribute__((ext_vector_type(8))) short bf16x8;
typedef __attribute__((ext_vector_type(4))) float f32x4;
typedef __attribute__((ext_vector_type(8))) unsigned short u16x8;
typedef __attribute__((ext_vector_type(4))) short s16x4;

__device__ inline short f2b(float f) {
  union { float f; unsigned u; } v; v.f = f;
  unsigned r = (v.u + 0x7FFFu + ((v.u >> 16) & 1u)) >> 16;
  return (short)r;
}

// ---- pre-kernel: W1 -> frag-sequential WTgF (8 blocks) ----
__global__ void p_w1(const float* __restrict__ w1_rel, const float* __restrict__ w1_root,
                     short* __restrict__ WTgF) {
  const int ct = blockIdx.x;             // 0..7
  const int ks = threadIdx.x >> 6, l = threadIdx.x & 63;
  const int col = ct*16 + (l & 15);
  const int kb  = ks*32 + (l >> 4)*8;
  short tmp[8];
  #pragma unroll
  for (int j = 0; j < 8; ++j) {
    const int k = kb + j;
    float v = (k < 64) ? w1_rel[k*H1D + col] : w1_root[(k - 64)*H1D + col];
    tmp[j] = f2b(v);
  }
  *(uint4*)&WTgF[(size_t)((ct*4 + ks)*64 + l)*8] = *(uint4*)tmp;
}

// ================= Kernel 1: per-graph encoder (+ folded weight transforms) ========
// Per graph: build A, h1pre = [A@X | X] @ W1, relu, then COMPLETE per-graph
// colsums (deg-weighted + plain) as bf16 -> SVb[g][256]. Tail blocks transform
// fc2 -> WF2g, w2/w3 -> W23T, fc1 -> fc1T (consumed by k2_fused, next launch).
__global__ __launch_bounds__(256, 5) void k1_enc(
    const float* __restrict__ x, const int* __restrict__ ei,
    const short* __restrict__ WTgF, const float* __restrict__ b1,
    short* __restrict__ SVb,
    const float* __restrict__ fc2_w, const float* __restrict__ w2_rel,
    const float* __restrict__ w2_root, const float* __restrict__ w3_rel,
    const float* __restrict__ w3_root, const float* __restrict__ fc1_w,
    short* __restrict__ WF2g, short* __restrict__ W23T, short* __restrict__ fc1T)
{
  __shared__ __align__(16) char smem[32000];
  const int g = blockIdx.x;
  const int tid = threadIdx.x;

  if (g >= NG) {
    // ---------- folded transform path ----------
    float* L = (float*)smem;
    const int bid = g - NG;               // 0..68
    if (bid < 63) {                       // fc2 -> frag-sequential WF2g
      const int c0 = bid*32;
      for (int i = tid; i < 4096; i += 256) {
        int k = i >> 5, c = i & 31;
        L[k*33 + c] = fc2_w[(size_t)k*OUTD + c0 + c];
      }
      __syncthreads();
      const int tl = tid >> 7;
      const int r  = tid & 127;
      const int ks = r >> 5;
      const int lp = r & 31;
      const int ct = bid*2 + tl;
      #pragma unroll
      for (int u = 0; u < 2; ++u) {
        const int l = lp*2 + u;
        const int cl = tl*16 + (l & 15);
        const int kb = ks*32 + (l >> 4)*8;
        short tmp[8];
        #pragma unroll
        for (int j = 0; j < 8; ++j) tmp[j] = f2b(L[(kb + j)*33 + cl]);
        *(uint4*)&WF2g[(size_t)((ct*4 + ks)*64 + l)*8] = *(uint4*)tmp;
      }
    } else if (bid < 67) {                // w2/w3 -> W23T (pitch 264), two passes
      const int cc = bid - 63;
      const int j0 = cc*32;
      const float* wrel  = (cc < 2) ? w2_rel  : w3_rel;
      const float* wroot = (cc < 2) ? w2_root : w3_root;
      const int jl = j0 & 63;
      const int c = tid >> 3, k0 = (tid & 7)*32;
      for (int i = tid; i < 4096; i += 256) {
        int k = i >> 5, cc2 = i & 31;
        L[k*33 + cc2] = wrel[k*H2D + jl + cc2];
      }
      __syncthreads();
      if (k0 < 128)
        for (int kk = 0; kk < 32; ++kk)
          W23T[(size_t)(j0 + c)*264 + k0 + kk] = f2b(L[(k0 + kk)*33 + c]);
      __syncthreads();
      for (int i = tid; i < 4096; i += 256) {
        int k = i >> 5, cc2 = i & 31;
        L[k*33 + cc2] = wroot[k*H2D + jl + cc2];
      }
      __syncthreads();
      if (k0 >= 128)
        for (int kk = 0; kk < 32; ++kk)
          W23T[(size_t)(j0 + c)*264 + k0 + kk] = f2b(L[(k0 + kk - 128)*33 + c]);
    } else {                              // fc1 -> fc1T (pitch 72)
      const int c0 = (bid - 67)*64;
      for (int i = tid; i < 4096; i += 256) {
        int k = i >> 6, c = i & 63;
        L[k*65 + c] = fc1_w[k*H1D + c0 + c];
      }
      __syncthreads();
      const int c = tid >> 2, k0 = (tid & 3)*16;
      for (int kk = 0; kk < 16; ++kk)
        fc1T[(size_t)(c0 + c)*72 + k0 + kk] = f2b(L[(k0 + kk)*65 + c]);
    }
    return;
  }

  // ---------- encoder path ----------
  short* Xb   = (short*)smem;               // 9216
  short* XbT  = (short*)(smem + 9216);      // 9216
  short* Ab   = (short*)(smem + 18432);     // 9216 (->AGb overlay)
  unsigned* Au32 = (unsigned*)(smem + 27648); // 4096 (packed u8 counts)
  float* Dg   = (float*)(smem + 31744);     // 256  (per-node degree weights)

  const int w = tid >> 6, l = tid & 63;

  // hoist ALL global loads (edges + x) to issue at block start
  const int e0 = g*EPG + tid*2;
  const int2 sp = *(const int2*)&ei[e0];
  const int2 dp = *(const int2*)&ei[ETOT + e0];
  const int s0 = sp.x & 63, d0 = dp.x & 63;
  const int s1 = sp.y & 63, d1 = dp.y & 63;
  const int n = tid >> 2, f0 = (tid & 3) * 16;
  const float* xr = x + (size_t)g*(NPG*IND) + n*IND + f0;
  float4 v0 = *(const float4*)&xr[0];
  float4 v1 = *(const float4*)&xr[4];
  float4 v2 = *(const float4*)&xr[8];
  float4 v3 = *(const float4*)&xr[12];

  for (int i = tid; i < 64*16; i += 256) Au32[i] = 0u;
  __syncthreads();                        // b1: Au32 zeroed -> atomics

  // adjacency: packed u8 counts (4 cells per u32, pitch 16 words)
  atomicAdd(&Au32[d0*16 + (s0 >> 2)], 1u << (8*(s0 & 3)));
  atomicAdd(&Au32[d1*16 + (s1 >> 2)], 1u << (8*(s1 & 3)));

  // stage Xb (row-major bf16, b128 stores) + XbT (transposed, scalar)
  {
    u16x8 lo, hi;
    lo[0]=(unsigned short)f2b(v0.x); lo[1]=(unsigned short)f2b(v0.y);
    lo[2]=(unsigned short)f2b(v0.z); lo[3]=(unsigned short)f2b(v0.w);
    lo[4]=(unsigned short)f2b(v1.x); lo[5]=(unsigned short)f2b(v1.y);
    lo[6]=(unsigned short)f2b(v1.z); lo[7]=(unsigned short)f2b(v1.w);
    hi[0]=(unsigned short)f2b(v2.x); hi[1]=(unsigned short)f2b(v2.y);
    hi[2]=(unsigned short)f2b(v2.z); hi[3]=(unsigned short)f2b(v2.w);
    hi[4]=(unsigned short)f2b(v3.x); hi[5]=(unsigned short)f2b(v3.y);
    hi[6]=(unsigned short)f2b(v3.z); hi[7]=(unsigned short)f2b(v3.w);
    *(u16x8*)&Xb[n*72 + f0]     = lo;
    *(u16x8*)&Xb[n*72 + f0 + 8] = hi;
    #pragma unroll
    for (int j = 0; j < 8; ++j) {
      XbT[(f0 + j)*72 + n]     = (short)lo[j];
      XbT[(f0 + 8 + j)*72 + n] = (short)hi[j];
    }
  }
  __syncthreads();                        // b2: atomics + staging done

  // cvt u8 -> bf16 into Ab (wave-local rows), b128 stores
  {
    const int row = tid >> 2, qw = tid & 3;
    unsigned wds[4];
    #pragma unroll
    for (int q = 0; q < 4; ++q) wds[q] = Au32[row*16 + qw*4 + q];
    auto pk = [](unsigned wv, int p) -> unsigned {
      unsigned c0 = (wv >> (16*p)) & 255u, c1 = (wv >> (16*p + 8)) & 255u;
      return (unsigned)(unsigned short)f2b((float)c0)
           | ((unsigned)(unsigned short)f2b((float)c1) << 16);
    };
    uint4 oA = { pk(wds[0],0), pk(wds[0],1), pk(wds[1],0), pk(wds[1],1) };
    uint4 oB = { pk(wds[2],0), pk(wds[2],1), pk(wds[3],0), pk(wds[3],1) };
    unsigned* abp = (unsigned*)&Ab[row*72 + qw*16];
    *(uint4*)&abp[0] = oA;
    *(uint4*)&abp[4] = oB;
  }

  // out-degree per node -> Dg[64] (SWAR colsum of Au32 over dst)
  {
    const int squad = tid >> 4;           // 0..15
    const int db = (tid & 15) * 4;        // dst slice
    unsigned ps = 0;
    #pragma unroll
    for (int i = 0; i < 4; ++i) ps += Au32[(db + i)*16 + squad];
    ps += __shfl_xor(ps, 1); ps += __shfl_xor(ps, 2);
    ps += __shfl_xor(ps, 4); ps += __shfl_xor(ps, 8);
    if ((tid & 15) == 0) {
      f32x4 dv = { (float)(ps & 255u), (float)((ps >> 8) & 255u),
                   (float)((ps >> 16) & 255u), (float)(ps >> 24) };
      *(f32x4*)&Dg[squad*4] = dv;
    }
  }

  const int rm = w*16;
  const int fr = l & 15;
  const int koff = (l >> 4) * 8;

  // phase 1: AG = A @ X — Ab rows own-wave, XbT all-waves (b2-covered)
  f32x4 agc[4];
  #pragma unroll
  for (int t = 0; t < 4; ++t) agc[t] = (f32x4){0.f,0.f,0.f,0.f};
  #pragma unroll
  for (int ks = 0; ks < 2; ++ks) {
    bf16x8 a = *(const bf16x8*)&Ab[(rm + fr)*72 + ks*32 + koff];
    #pragma unroll
    for (int t = 0; t < 4; ++t) {
      bf16x8 b = *(const bf16x8*)&XbT[(t*16 + fr)*72 + ks*32 + koff];
      agc[t] = __builtin_amdgcn_mfma_f32_16x16x32_bf16(a, b, agc[t], 0, 0, 0);
    }
  }

  // hoist this wave's 2 W1 col-tiles (global, L1/L2-hot) while AGb writes drain
  bf16x8 bfr[2][4];
  #pragma unroll
  for (int ct2 = 0; ct2 < 2; ++ct2)
    #pragma unroll
    for (int ks = 0; ks < 4; ++ks)
      bfr[ct2][ks] = *(const bf16x8*)&WTgF[(size_t)(((2*w + ct2)*4 + ks)*64 + l)*8];

  // overlay: write AG bf16 over own Ab rows
  short* AGb = Ab;
  #pragma unroll
  for (int t = 0; t < 4; ++t)
    #pragma unroll
    for (int r = 0; r < 4; ++r)
      AGb[(rm + (l>>4)*4 + r)*72 + t*16 + fr] = f2b(agc[t][r]);

  __syncthreads();                        // b3: AGb + Dg all-wave visible

  // phase 2: wave w owns col-tiles {2w, 2w+1} over ALL 64 rows
  // -> complete per-graph colsums (plain + deg-weighted) within the wave.
  const float bb0 = b1[(2*w)*16 + fr];
  const float bb1 = b1[(2*w + 1)*16 + fr];
  float hs0 = 0.f, ws0 = 0.f, hs1 = 0.f, ws1 = 0.f;
  #pragma unroll
  for (int rt = 0; rt < 4; ++rt) {
    bf16x8 afr[4];
    #pragma unroll
    for (int ks = 0; ks < 4; ++ks)
      afr[ks] = (ks < 2)
        ? *(const bf16x8*)&AGb[(rt*16 + fr)*72 + ks*32 + koff]
        : *(const bf16x8*)&Xb[(rt*16 + fr)*72 + (ks - 2)*32 + koff];
    f32x4 a0 = (f32x4){0.f,0.f,0.f,0.f}, a1 = (f32x4){0.f,0.f,0.f,0.f};
    #pragma unroll
    for (int ks = 0; ks < 4; ++ks) {
      a0 = __builtin_amdgcn_mfma_f32_16x16x32_bf16(afr[ks], bfr[0][ks], a0, 0, 0, 0);
      a1 = __builtin_amdgcn_mfma_f32_16x16x32_bf16(afr[ks], bfr[1][ks], a1, 0, 0, 0);
    }
    f32x4 dgv = *(const f32x4*)&Dg[rt*16 + (l >> 4)*4];
    #pragma unroll
    for (int r = 0; r < 4; ++r) {
      float va = fmaxf(a0[r] + bb0, 0.f);
      float vb = fmaxf(a1[r] + bb1, 0.f);
      hs0 += va; ws0 += dgv[r]*va;
      hs1 += vb; ws1 += dgv[r]*vb;
    }
  }
  hs0 += __shfl_down(hs0, 32); ws0 += __shfl_down(ws0, 32);
  hs1 += __shfl_down(hs1, 32); ws1 += __shfl_down(ws1, 32);
  hs0 += __shfl_down(hs0, 16); ws0 += __shfl_down(ws0, 16);
  hs1 += __shfl_down(hs1, 16); ws1 += __shfl_down(ws1, 16);
  if (l < 16) {
    short* svg = SVb + (size_t)g*256;
    svg[(2*w)*16 + l]           = f2b(ws0);
    svg[(2*w + 1)*16 + l]       = f2b(ws1);
    svg[128 + (2*w)*16 + l]     = f2b(hs0);
    svg[128 + (2*w + 1)*16 + l] = f2b(hs1);
  }
}

// ================= Kernel 2 (fused): latent recompute + decoder tile ==========
// Grid (64 groups, 21 col-blocks). Each block: conv2/3-mean + reparam + fc1
// for its 32 graphs (L2-resident inputs, ~40 MFMAs -> cheap to recompute per
// col-block), h kept in LDS, then 32x96 decode tile with SWAPPED mfma operands
// so each lane holds 4 consecutive output cols -> float4 sigmoid stores.
__global__ __launch_bounds__(256) void k2_fused(
    const short* __restrict__ SVb, const short* __restrict__ W23T,
    const float* __restrict__ b2, const float* __restrict__ b3,
    const float* __restrict__ eps, const short* __restrict__ fc1T,
    const float* __restrict__ fc1_b, const short* __restrict__ WF2g,
    const float* __restrict__ fc2_b,
    float* __restrict__ out_mu, float* __restrict__ out_lv,
    float* __restrict__ recon)
{
  __shared__ short SV[32*264];   // 16896
  __shared__ short Zt[32*72];    // 4608
  __shared__ short Hs[32*136];   // 8704
  const int g0 = blockIdx.x * 32;
  const int by = blockIdx.y;
  const int tid = threadIdx.x;
  const int w = tid >> 6, l = tid & 63;
  const int s = w >> 1;          // row-half (16 graphs)
  const int h = w & 1;           // col-half
  const int fr = l & 15;
  const int koff = (l >> 4) * 8;

  for (int i = tid; i < 32*64; i += 256) {
    const int r = i >> 6, kq = (i & 63)*4;
    *(s16x4*)&SV[r*264 + kq] = *(const s16x4*)&SVb[(size_t)(g0 + r)*256 + kq];
  }
  __syncthreads();

  // conv2/3 + mean
  f32x4 acc[4];
  #pragma unroll
  for (int t = 0; t < 4; ++t) acc[t] = (f32x4){0.f,0.f,0.f,0.f};
  #pragma unroll
  for (int ks = 0; ks < 8; ++ks) {
    bf16x8 a = *(const bf16x8*)&SV[(s*16 + fr)*264 + ks*32 + koff];
    #pragma unroll
    for (int j = 0; j < 2; ++j) {
      bf16x8 bm = *(const bf16x8*)&W23T[((2*h + j)*16 + fr)*264 + ks*32 + koff];
      bf16x8 bl = *(const bf16x8*)&W23T[((2*h + j + 4)*16 + fr)*264 + ks*32 + koff];
      acc[j]     = __builtin_amdgcn_mfma_f32_16x16x32_bf16(a, bm, acc[j], 0, 0, 0);
      acc[2 + j] = __builtin_amdgcn_mfma_f32_16x16x32_bf16(a, bl, acc[2 + j], 0, 0, 0);
    }
  }
  #pragma unroll
  for (int j = 0; j < 2; ++j) {
    const int col = (2*h + j)*16 + fr;
    const float bb2 = b2[col], bb3 = b3[col];
    #pragma unroll
    for (int r = 0; r < 4; ++r) {
      const int row = s*16 + (l>>4)*4 + r;
      const size_t gg = (size_t)(g0 + row);
      float mu = acc[j][r]     * (1.f/64.f) + bb2;
      float lv = acc[2 + j][r] * (1.f/64.f) + bb3;
      if (by == 0) {
        out_mu[gg*64 + col] = mu;
        out_lv[gg*64 + col] = lv;
      }
      float z = mu + eps[gg*64 + col] * __expf(0.5f*lv);
      Zt[row*72 + col] = f2b(z);
    }
  }
  __syncthreads();

  // fc1 -> Hs (row-major, pitch 136)
  f32x4 hacc[4];
  #pragma unroll
  for (int t = 0; t < 4; ++t) hacc[t] = (f32x4){0.f,0.f,0.f,0.f};
  #pragma unroll
  for (int ks = 0; ks < 2; ++ks) {
    bf16x8 a = *(const bf16x8*)&Zt[(s*16 + fr)*72 + ks*32 + koff];
    #pragma unroll
    for (int j = 0; j < 4; ++j) {
      bf16x8 b = *(const bf16x8*)&fc1T[((h*4 + j)*16 + fr)*72 + ks*32 + koff];
      hacc[j] = __builtin_amdgcn_mfma_f32_16x16x32_bf16(a, b, hacc[j], 0, 0, 0);
    }
  }
  #pragma unroll
  for (int j = 0; j < 4; ++j) {
    const int col = (h*4 + j)*16 + fr;      // 0..127
    const float bb = fc1_b[col];
    #pragma unroll
    for (int r = 0; r < 4; ++r) {
      const int row = s*16 + (l>>4)*4 + r;  // 0..31
      Hs[row*136 + col] = f2b(fmaxf(hacc[j][r] + bb, 0.f));
    }
  }
  __syncthreads();

  // decode: wave (s,h) -> rows 16s..16s+15, col-tiles by*6 + h*3 + {0,1,2}
  // SWAPPED operands: acc'[t][r] holds row (l&15), cols colq..colq+3.
  bf16x8 ah[4];
  #pragma unroll
  for (int ks = 0; ks < 4; ++ks)
    ah[ks] = *(const bf16x8*)&Hs[(s*16 + fr)*136 + ks*32 + koff];

  f32x4 dcc[3];
  #pragma unroll
  for (int t = 0; t < 3; ++t) dcc[t] = (f32x4){0.f,0.f,0.f,0.f};
  #pragma unroll
  for (int ks = 0; ks < 4; ++ks) {
    #pragma unroll
    for (int t = 0; t < 3; ++t) {
      const int ct = by*6 + h*3 + t;
      bf16x8 bw = *(const bf16x8*)&WF2g[(size_t)((ct*4 + ks)*64 + l)*8];
      dcc[t] = __builtin_amdgcn_mfma_f32_16x16x32_bf16(bw, ah[ks], dcc[t], 0, 0, 0);
    }
  }

  #pragma unroll
  for (int t = 0; t < 3; ++t) {
    const int colq = (by*6 + h*3 + t)*16 + (l >> 4)*4;
    const int row  = g0 + s*16 + fr;
    const float4 bb = *(const float4*)&fc2_b[colq];
    float4 o;
    o.x = 1.f/(1.f + __expf(-(dcc[t][0] + bb.x)));
    o.y = 1.f/(1.f + __expf(-(dcc[t][1] + bb.y)));
    o.z = 1.f/(1.f + __expf(-(dcc[t][2] + bb.z)));
    o.w = 1.f/(1.f + __expf(-(dcc[t][3] + bb.w)));
    *(float4*)&recon[(size_t)row*OUTD + colq] = o;
  }
}

extern "C" void kernel_launch(void* const* d_in, const int* in_sizes, int n_in,
                              void* d_out, int out_size, void* d_ws, size_t ws_size,
                              hipStream_t stream) {
  const float* x       = (const float*)d_in[0];
  const int*   ei      = (const int*)d_in[1];
  const float* eps     = (const float*)d_in[3];
  const float* w1_rel  = (const float*)d_in[4];
  const float* b1      = (const float*)d_in[5];
  const float* w1_root = (const float*)d_in[6];
  const float* w2_rel  = (const float*)d_in[7];
  const float* b2      = (const float*)d_in[8];
  const float* w2_root = (const float*)d_in[9];
  const float* w3_rel  = (const float*)d_in[10];
  const float* b3      = (const float*)d_in[11];
  const float* w3_root = (const float*)d_in[12];
  const float* fc1_w   = (const float*)d_in[13];
  const float* fc1_b   = (const float*)d_in[14];
  const float* fc2_w   = (const float*)d_in[15];
  const float* fc2_b   = (const float*)d_in[16];

  float* recon  = (float*)d_out;
  float* out_mu = recon + (size_t)NG*OUTD;
  float* out_lv = out_mu + (size_t)NG*H2D;

  char* p = (char*)d_ws;
  short* WTgF  = (short*)p;              p += 8*4*64*8*2;           // 32768
  short* WF2g  = (short*)p;              p += 126*4*64*8*2;         // 516096
  short* fc1T  = (short*)p;              p += 128*72*2;             // 18432
  short* W23T  = (short*)p;              p += 128*264*2;            // 67584
  short* SVb   = (short*)p;                                          // 1 MB

  p_w1<<<8, 256, 0, stream>>>(w1_rel, w1_root, WTgF);
  k1_enc<<<NG + 69, 256, 0, stream>>>(x, ei, WTgF, b1, SVb,
      fc2_w, w2_rel, w2_root, w3_rel, w3_root, fc1_w, WF2g, W23T, fc1T);
  k2_fused<<<dim3(64, 21), 256, 0, stream>>>(SVb, W23T, b2, b3, eps, fc1T, fc1_b,
                                             WF2g, fc2_b, out_mu, out_lv, recon);
}

// Round 6
// 135.214 us; speedup vs baseline: 1.0545x; 1.0545x over previous
//
#include <hip/hip_runtime.h>
#include <math.h>

#define NG 2048
#define NPG 64
#define EPG 512
#define ETOT (NG*EPG)
#define IND 64
#define H1D 128
#define H2D 64
#define OUTD 2016

typedef __attribute__((ext_vector_type(8))) short bf16x8;
typedef __attribute__((ext_vector_type(4))) float f32x4;
typedef __attribute__((ext_vector_type(8))) unsigned short u16x8;
typedef __attribute__((ext_vector_type(4))) short s16x4;

__device__ inline short f2b(float f) {
  union { float f; unsigned u; } v; v.f = f;
  unsigned r = (v.u + 0x7FFFu + ((v.u >> 16) & 1u)) >> 16;
  return (short)r;
}

// ---- pre-kernel: W1 frag transform + W23T + fc1T transforms ----
// Blocks 0..7: w1 -> WTgF.  8..11: w2/w3 -> W23T.  12..13: fc1 -> fc1T.
__global__ void p_w1(const float* __restrict__ w1_rel, const float* __restrict__ w1_root,
                     short* __restrict__ WTgF,
                     const float* __restrict__ w2_rel, const float* __restrict__ w2_root,
                     const float* __restrict__ w3_rel, const float* __restrict__ w3_root,
                     const float* __restrict__ fc1_w,
                     short* __restrict__ W23T, short* __restrict__ fc1T) {
  __shared__ float L[4224];
  const int b = blockIdx.x;
  const int tid = threadIdx.x;
  if (b < 8) {
    const int ct = b;
    const int ks = tid >> 6, l = tid & 63;
    const int col = ct*16 + (l & 15);
    const int kb  = ks*32 + (l >> 4)*8;
    short tmp[8];
    #pragma unroll
    for (int j = 0; j < 8; ++j) {
      const int k = kb + j;
      float v = (k < 64) ? w1_rel[k*H1D + col] : w1_root[(k - 64)*H1D + col];
      tmp[j] = f2b(v);
    }
    *(uint4*)&WTgF[(size_t)((ct*4 + ks)*64 + l)*8] = *(uint4*)tmp;
  } else if (b < 12) {                       // w2/w3 -> W23T (pitch 264), two passes
    const int cc = b - 8;
    const int j0 = cc*32;
    const float* wrel  = (cc < 2) ? w2_rel  : w3_rel;
    const float* wroot = (cc < 2) ? w2_root : w3_root;
    const int jl = j0 & 63;
    const int c = tid >> 3, k0 = (tid & 7)*32;
    for (int i = tid; i < 4096; i += 256) {
      int k = i >> 5, cc2 = i & 31;
      L[k*33 + cc2] = wrel[k*H2D + jl + cc2];
    }
    __syncthreads();
    if (k0 < 128)
      for (int kk = 0; kk < 32; ++kk)
        W23T[(size_t)(j0 + c)*264 + k0 + kk] = f2b(L[(k0 + kk)*33 + c]);
    __syncthreads();
    for (int i = tid; i < 4096; i += 256) {
      int k = i >> 5, cc2 = i & 31;
      L[k*33 + cc2] = wroot[k*H2D + jl + cc2];
    }
    __syncthreads();
    if (k0 >= 128)
      for (int kk = 0; kk < 32; ++kk)
        W23T[(size_t)(j0 + c)*264 + k0 + kk] = f2b(L[(k0 + kk - 128)*33 + c]);
  } else {                                   // fc1 -> fc1T (pitch 72)
    const int c0 = (b - 12)*64;
    for (int i = tid; i < 4096; i += 256) {
      int k = i >> 6, c = i & 63;
      L[k*65 + c] = fc1_w[k*H1D + c0 + c];
    }
    __syncthreads();
    const int c = tid >> 2, k0 = (tid & 3)*16;
    for (int kk = 0; kk < 16; ++kk)
      fc1T[(size_t)(c0 + c)*72 + k0 + kk] = f2b(L[(k0 + kk)*65 + c]);
  }
}

// ================= Kernel 1: per-graph encoder (+ WF2g transform blocks) ========
// LDS trimmed to 31744 B (Dg lives in Ab row padding) -> 5 blocks/CU.
__global__ __launch_bounds__(256, 5) void k1_enc(
    const float* __restrict__ x, const int* __restrict__ ei,
    const short* __restrict__ WTgF, const float* __restrict__ b1,
    short* __restrict__ SVb,
    const float* __restrict__ fc2_w, short* __restrict__ WF2g)
{
  __shared__ __align__(16) char smem[31744];
  const int g = blockIdx.x;
  const int tid = threadIdx.x;

  if (g >= NG) {                             // fc2 -> frag-sequential WF2g (63 blocks)
    float* L = (float*)smem;
    const int bid = g - NG;
    const int c0 = bid*32;
    for (int i = tid; i < 4096; i += 256) {
      int k = i >> 5, c = i & 31;
      L[k*33 + c] = fc2_w[(size_t)k*OUTD + c0 + c];
    }
    __syncthreads();
    const int tl = tid >> 7;
    const int r  = tid & 127;
    const int ks = r >> 5;
    const int lp = r & 31;
    const int ct = bid*2 + tl;
    #pragma unroll
    for (int u = 0; u < 2; ++u) {
      const int l = lp*2 + u;
      const int cl = tl*16 + (l & 15);
      const int kb = ks*32 + (l >> 4)*8;
      short tmp[8];
      #pragma unroll
      for (int j = 0; j < 8; ++j) tmp[j] = f2b(L[(kb + j)*33 + cl]);
      *(uint4*)&WF2g[(size_t)((ct*4 + ks)*64 + l)*8] = *(uint4*)tmp;
    }
    return;
  }

  // ---------- encoder path ----------
  short* Xb   = (short*)smem;               // 9216 (rows: 64 data + 8 pad shorts)
  short* XbT  = (short*)(smem + 9216);      // 9216
  short* Ab   = (short*)(smem + 18432);     // 9216 (->AGb overlay; pad holds Dg)
  unsigned* Au32 = (unsigned*)(smem + 27648); // 4096 (packed u8 counts)
  // Dg[row] stored as float at Ab[row*72 + 64] (row pad bytes 128..131)

  const int w = tid >> 6, l = tid & 63;

  // hoist ALL global loads (edges + x) to issue at block start
  const int e0 = g*EPG + tid*2;
  const int2 sp = *(const int2*)&ei[e0];
  const int2 dp = *(const int2*)&ei[ETOT + e0];
  const int s0 = sp.x & 63, d0 = dp.x & 63;
  const int s1 = sp.y & 63, d1 = dp.y & 63;
  const int n = tid >> 2, f0 = (tid & 3) * 16;
  const float* xr = x + (size_t)g*(NPG*IND) + n*IND + f0;
  float4 v0 = *(const float4*)&xr[0];
  float4 v1 = *(const float4*)&xr[4];
  float4 v2 = *(const float4*)&xr[8];
  float4 v3 = *(const float4*)&xr[12];

  for (int i = tid; i < 64*16; i += 256) Au32[i] = 0u;
  __syncthreads();                        // b1: Au32 zeroed -> atomics

  // adjacency: packed u8 counts (4 cells per u32, pitch 16 words)
  atomicAdd(&Au32[d0*16 + (s0 >> 2)], 1u << (8*(s0 & 3)));
  atomicAdd(&Au32[d1*16 + (s1 >> 2)], 1u << (8*(s1 & 3)));

  // stage Xb (row-major bf16, b128 stores) + XbT (transposed, scalar)
  {
    u16x8 lo, hi;
    lo[0]=(unsigned short)f2b(v0.x); lo[1]=(unsigned short)f2b(v0.y);
    lo[2]=(unsigned short)f2b(v0.z); lo[3]=(unsigned short)f2b(v0.w);
    lo[4]=(unsigned short)f2b(v1.x); lo[5]=(unsigned short)f2b(v1.y);
    lo[6]=(unsigned short)f2b(v1.z); lo[7]=(unsigned short)f2b(v1.w);
    hi[0]=(unsigned short)f2b(v2.x); hi[1]=(unsigned short)f2b(v2.y);
    hi[2]=(unsigned short)f2b(v2.z); hi[3]=(unsigned short)f2b(v2.w);
    hi[4]=(unsigned short)f2b(v3.x); hi[5]=(unsigned short)f2b(v3.y);
    hi[6]=(unsigned short)f2b(v3.z); hi[7]=(unsigned short)f2b(v3.w);
    *(u16x8*)&Xb[n*72 + f0]     = lo;
    *(u16x8*)&Xb[n*72 + f0 + 8] = hi;
    #pragma unroll
    for (int j = 0; j < 8; ++j) {
      XbT[(f0 + j)*72 + n]     = (short)lo[j];
      XbT[(f0 + 8 + j)*72 + n] = (short)hi[j];
    }
  }
  __syncthreads();                        // b2: atomics + staging done

  // cvt u8 -> bf16 into Ab (wave-local rows), b128 stores
  {
    const int row = tid >> 2, qw = tid & 3;
    unsigned wds[4];
    #pragma unroll
    for (int q = 0; q < 4; ++q) wds[q] = Au32[row*16 + qw*4 + q];
    auto pk = [](unsigned wv, int p) -> unsigned {
      unsigned c0 = (wv >> (16*p)) & 255u, c1 = (wv >> (16*p + 8)) & 255u;
      return (unsigned)(unsigned short)f2b((float)c0)
           | ((unsigned)(unsigned short)f2b((float)c1) << 16);
    };
    uint4 oA = { pk(wds[0],0), pk(wds[0],1), pk(wds[1],0), pk(wds[1],1) };
    uint4 oB = { pk(wds[2],0), pk(wds[2],1), pk(wds[3],0), pk(wds[3],1) };
    unsigned* abp = (unsigned*)&Ab[row*72 + qw*16];
    *(uint4*)&abp[0] = oA;
    *(uint4*)&abp[4] = oB;
  }

  // out-degree per node -> Ab row pad (SWAR colsum of Au32 over dst)
  {
    const int squad = tid >> 4;           // 0..15 (node quad)
    const int db = (tid & 15) * 4;        // dst slice
    unsigned ps = 0;
    #pragma unroll
    for (int i = 0; i < 4; ++i) ps += Au32[(db + i)*16 + squad];
    ps += __shfl_xor(ps, 1); ps += __shfl_xor(ps, 2);
    ps += __shfl_xor(ps, 4); ps += __shfl_xor(ps, 8);
    if ((tid & 15) == 0) {
      #pragma unroll
      for (int i = 0; i < 4; ++i)
        *(float*)&Ab[(squad*4 + i)*72 + 64] = (float)((ps >> (8*i)) & 255u);
    }
  }

  const int rm = w*16;
  const int fr = l & 15;
  const int koff = (l >> 4) * 8;

  // phase 1: AG = A @ X — Ab rows own-wave, XbT all-waves (b2-covered)
  f32x4 agc[4];
  #pragma unroll
  for (int t = 0; t < 4; ++t) agc[t] = (f32x4){0.f,0.f,0.f,0.f};
  #pragma unroll
  for (int ks = 0; ks < 2; ++ks) {
    bf16x8 a = *(const bf16x8*)&Ab[(rm + fr)*72 + ks*32 + koff];
    #pragma unroll
    for (int t = 0; t < 4; ++t) {
      bf16x8 b = *(const bf16x8*)&XbT[(t*16 + fr)*72 + ks*32 + koff];
      agc[t] = __builtin_amdgcn_mfma_f32_16x16x32_bf16(a, b, agc[t], 0, 0, 0);
    }
  }

  // hoist this wave's 2 W1 col-tiles (global, L1/L2-hot) while AGb writes drain
  bf16x8 bfr[2][4];
  #pragma unroll
  for (int ct2 = 0; ct2 < 2; ++ct2)
    #pragma unroll
    for (int ks = 0; ks < 4; ++ks)
      bfr[ct2][ks] = *(const bf16x8*)&WTgF[(size_t)(((2*w + ct2)*4 + ks)*64 + l)*8];

  // overlay: write AG bf16 over own Ab rows (cols 0..63 only; pad preserved)
  short* AGb = Ab;
  #pragma unroll
  for (int t = 0; t < 4; ++t)
    #pragma unroll
    for (int r = 0; r < 4; ++r)
      AGb[(rm + (l>>4)*4 + r)*72 + t*16 + fr] = f2b(agc[t][r]);

  __syncthreads();                        // b3: AGb + Dg all-wave visible

  // phase 2: wave w owns col-tiles {2w, 2w+1} over ALL 64 rows
  const float bb0 = b1[(2*w)*16 + fr];
  const float bb1 = b1[(2*w + 1)*16 + fr];
  float hs0 = 0.f, ws0 = 0.f, hs1 = 0.f, ws1 = 0.f;
  #pragma unroll
  for (int rt = 0; rt < 4; ++rt) {
    bf16x8 afr[4];
    #pragma unroll
    for (int ks = 0; ks < 4; ++ks)
      afr[ks] = (ks < 2)
        ? *(const bf16x8*)&AGb[(rt*16 + fr)*72 + ks*32 + koff]
        : *(const bf16x8*)&Xb[(rt*16 + fr)*72 + (ks - 2)*32 + koff];
    f32x4 a0 = (f32x4){0.f,0.f,0.f,0.f}, a1 = (f32x4){0.f,0.f,0.f,0.f};
    #pragma unroll
    for (int ks = 0; ks < 4; ++ks) {
      a0 = __builtin_amdgcn_mfma_f32_16x16x32_bf16(afr[ks], bfr[0][ks], a0, 0, 0, 0);
      a1 = __builtin_amdgcn_mfma_f32_16x16x32_bf16(afr[ks], bfr[1][ks], a1, 0, 0, 0);
    }
    #pragma unroll
    for (int r = 0; r < 4; ++r) {
      const float dgr = *(const float*)&Ab[(rt*16 + (l>>4)*4 + r)*72 + 64];
      float va = fmaxf(a0[r] + bb0, 0.f);
      float vb = fmaxf(a1[r] + bb1, 0.f);
      hs0 += va; ws0 += dgr*va;
      hs1 += vb; ws1 += dgr*vb;
    }
  }
  hs0 += __shfl_down(hs0, 32); ws0 += __shfl_down(ws0, 32);
  hs1 += __shfl_down(hs1, 32); ws1 += __shfl_down(ws1, 32);
  hs0 += __shfl_down(hs0, 16); ws0 += __shfl_down(ws0, 16);
  hs1 += __shfl_down(hs1, 16); ws1 += __shfl_down(ws1, 16);
  if (l < 16) {
    short* svg = SVb + (size_t)g*256;
    svg[(2*w)*16 + l]           = f2b(ws0);
    svg[(2*w + 1)*16 + l]       = f2b(ws1);
    svg[128 + (2*w)*16 + l]     = f2b(hs0);
    svg[128 + (2*w + 1)*16 + l] = f2b(hs1);
  }
}

// ================= Kernel 1b: batched conv2/3-mean + reparam + fc1 ==========
// SWAPPED mfma operands -> each lane holds 4 consecutive cols: float4/short4 I/O.
__global__ __launch_bounds__(256) void k1b_latent(
    const short* __restrict__ SVb, const short* __restrict__ W23T,
    const float* __restrict__ b2, const float* __restrict__ b3,
    const float* __restrict__ eps, const short* __restrict__ fc1T,
    const float* __restrict__ fc1_b,
    float* __restrict__ out_mu, float* __restrict__ out_lv, short* __restrict__ hbufF)
{
  __shared__ short SV[32*264];
  __shared__ short Zt[32*72];
  const int g0 = blockIdx.x * 32;
  const int tid = threadIdx.x;
  const int w = tid >> 6, l = tid & 63;
  const int s = w >> 1;
  const int h = w & 1;
  const int fr = l & 15;
  const int koff = (l >> 4) * 8;

  for (int i = tid; i < 32*64; i += 256) {
    const int r = i >> 6, kq = (i & 63)*4;
    *(s16x4*)&SV[r*264 + kq] = *(const s16x4*)&SVb[(size_t)(g0 + r)*256 + kq];
  }
  __syncthreads();

  // conv2/3 + mean, D[col][row] via swapped operands
  f32x4 acc[4];
  #pragma unroll
  for (int t = 0; t < 4; ++t) acc[t] = (f32x4){0.f,0.f,0.f,0.f};
  #pragma unroll
  for (int ks = 0; ks < 8; ++ks) {
    bf16x8 a = *(const bf16x8*)&SV[(s*16 + fr)*264 + ks*32 + koff];
    #pragma unroll
    for (int j = 0; j < 2; ++j) {
      bf16x8 bm = *(const bf16x8*)&W23T[((2*h + j)*16 + fr)*264 + ks*32 + koff];
      bf16x8 bl = *(const bf16x8*)&W23T[((2*h + j + 4)*16 + fr)*264 + ks*32 + koff];
      acc[j]     = __builtin_amdgcn_mfma_f32_16x16x32_bf16(bm, a, acc[j], 0, 0, 0);
      acc[2 + j] = __builtin_amdgcn_mfma_f32_16x16x32_bf16(bl, a, acc[2 + j], 0, 0, 0);
    }
  }
  {
    const int grow = s*16 + (l & 15);
    const size_t gg = (size_t)(g0 + grow);
    #pragma unroll
    for (int j = 0; j < 2; ++j) {
      const int c0 = (2*h + j)*16 + (l >> 4)*4;
      const float4 bb2 = *(const float4*)&b2[c0];
      const float4 bb3 = *(const float4*)&b3[c0];
      const float4 ev  = *(const float4*)&eps[gg*64 + c0];
      float4 mu, lv;
      mu.x = acc[j][0]*(1.f/64.f) + bb2.x;  lv.x = acc[2+j][0]*(1.f/64.f) + bb3.x;
      mu.y = acc[j][1]*(1.f/64.f) + bb2.y;  lv.y = acc[2+j][1]*(1.f/64.f) + bb3.y;
      mu.z = acc[j][2]*(1.f/64.f) + bb2.z;  lv.z = acc[2+j][2]*(1.f/64.f) + bb3.z;
      mu.w = acc[j][3]*(1.f/64.f) + bb2.w;  lv.w = acc[2+j][3]*(1.f/64.f) + bb3.w;
      *(float4*)&out_mu[gg*64 + c0] = mu;
      *(float4*)&out_lv[gg*64 + c0] = lv;
      s16x4 zs;
      zs[0] = f2b(mu.x + ev.x * __expf(0.5f*lv.x));
      zs[1] = f2b(mu.y + ev.y * __expf(0.5f*lv.y));
      zs[2] = f2b(mu.z + ev.z * __expf(0.5f*lv.z));
      zs[3] = f2b(mu.w + ev.w * __expf(0.5f*lv.w));
      *(s16x4*)&Zt[grow*72 + c0] = zs;
    }
  }
  __syncthreads();

  // fc1, D[col][row] via swapped operands -> contiguous short4 hbuf stores
  f32x4 hacc[4];
  #pragma unroll
  for (int t = 0; t < 4; ++t) hacc[t] = (f32x4){0.f,0.f,0.f,0.f};
  #pragma unroll
  for (int ks = 0; ks < 2; ++ks) {
    bf16x8 a = *(const bf16x8*)&Zt[(s*16 + fr)*72 + ks*32 + koff];
    #pragma unroll
    for (int j = 0; j < 4; ++j) {
      bf16x8 b = *(const bf16x8*)&fc1T[((h*4 + j)*16 + fr)*72 + ks*32 + koff];
      hacc[j] = __builtin_amdgcn_mfma_f32_16x16x32_bf16(b, a, hacc[j], 0, 0, 0);
    }
  }
  {
    const int row = s*16 + (l & 15);      // 0..31
    const int rt2 = blockIdx.x*2 + (row >> 4);
    #pragma unroll
    for (int j = 0; j < 4; ++j) {
      const int c0 = (h*4 + j)*16 + (l >> 4)*4;   // 0..124, mult of 4
      const float4 bb = *(const float4*)&fc1_b[c0];
      s16x4 hv;
      hv[0] = f2b(fmaxf(hacc[j][0] + bb.x, 0.f));
      hv[1] = f2b(fmaxf(hacc[j][1] + bb.y, 0.f));
      hv[2] = f2b(fmaxf(hacc[j][2] + bb.z, 0.f));
      hv[3] = f2b(fmaxf(hacc[j][3] + bb.w, 0.f));
      const int ks2 = c0 >> 5;
      const int q   = (c0 >> 3) & 3;
      const int j8  = c0 & 7;
      const int lane = (row & 15) + 16*q;
      *(s16x4*)&hbufF[(size_t)((rt2*4 + ks2)*64 + lane)*8 + j8] = hv;
    }
  }
}

// ================= Kernel 2: decoder GEMM — swapped operands, float4 stores ==========
__global__ __launch_bounds__(256, 8) void k2_decoder(
    const short* __restrict__ hbufF, const short* __restrict__ WF2g,
    const float* __restrict__ fc2_b, float* __restrict__ recon)
{
  const int bx = blockIdx.x, by = blockIdx.y;
  const int tid = threadIdx.x;
  const int w = tid >> 6, l = tid & 63;
  const int rt = bx*4 + w;                 // row-tile (16 rows)

  bf16x8 ah[4];
  #pragma unroll
  for (int ks = 0; ks < 4; ++ks)
    ah[ks] = *(const bf16x8*)&hbufF[(size_t)((rt*4 + ks)*64 + l)*8];

  f32x4 acc[6];
  #pragma unroll
  for (int t = 0; t < 6; ++t) acc[t] = (f32x4){0.f,0.f,0.f,0.f};

  #pragma unroll
  for (int ks = 0; ks < 4; ++ks) {
    #pragma unroll
    for (int t = 0; t < 6; ++t) {
      const int ct = by*6 + t;
      bf16x8 bw = *(const bf16x8*)&WF2g[(size_t)((ct*4 + ks)*64 + l)*8];
      acc[t] = __builtin_amdgcn_mfma_f32_16x16x32_bf16(bw, ah[ks], acc[t], 0, 0, 0);
    }
  }

  const int row = bx*64 + w*16 + (l & 15);
  #pragma unroll
  for (int t = 0; t < 6; ++t) {
    const int colq = (by*6 + t)*16 + (l >> 4)*4;
    const float4 bb = *(const float4*)&fc2_b[colq];
    float4 o;
    o.x = 1.f/(1.f + __expf(-(acc[t][0] + bb.x)));
    o.y = 1.f/(1.f + __expf(-(acc[t][1] + bb.y)));
    o.z = 1.f/(1.f + __expf(-(acc[t][2] + bb.z)));
    o.w = 1.f/(1.f + __expf(-(acc[t][3] + bb.w)));
    *(float4*)&recon[(size_t)row*OUTD + colq] = o;
  }
}

extern "C" void kernel_launch(void* const* d_in, const int* in_sizes, int n_in,
                              void* d_out, int out_size, void* d_ws, size_t ws_size,
                              hipStream_t stream) {
  const float* x       = (const float*)d_in[0];
  const int*   ei      = (const int*)d_in[1];
  const float* eps     = (const float*)d_in[3];
  const float* w1_rel  = (const float*)d_in[4];
  const float* b1      = (const float*)d_in[5];
  const float* w1_root = (const float*)d_in[6];
  const float* w2_rel  = (const float*)d_in[7];
  const float* b2      = (const float*)d_in[8];
  const float* w2_root = (const float*)d_in[9];
  const float* w3_rel  = (const float*)d_in[10];
  const float* b3      = (const float*)d_in[11];
  const float* w3_root = (const float*)d_in[12];
  const float* fc1_w   = (const float*)d_in[13];
  const float* fc1_b   = (const float*)d_in[14];
  const float* fc2_w   = (const float*)d_in[15];
  const float* fc2_b   = (const float*)d_in[16];

  float* recon  = (float*)d_out;
  float* out_mu = recon + (size_t)NG*OUTD;
  float* out_lv = out_mu + (size_t)NG*H2D;

  char* p = (char*)d_ws;
  short* WTgF  = (short*)p;              p += 8*4*64*8*2;           // 32768
  short* WF2g  = (short*)p;              p += 126*4*64*8*2;         // 516096
  short* fc1T  = (short*)p;              p += 128*72*2;             // 18432
  short* W23T  = (short*)p;              p += 128*264*2;            // 67584
  short* SVb   = (short*)p;              p += (size_t)NG*256*2;     // 1 MB
  short* hbufF = (short*)p;                                          // 524288

  p_w1<<<14, 256, 0, stream>>>(w1_rel, w1_root, WTgF,
                               w2_rel, w2_root, w3_rel, w3_root,
                               fc1_w, W23T, fc1T);
  k1_enc<<<NG + 63, 256, 0, stream>>>(x, ei, WTgF, b1, SVb, fc2_w, WF2g);
  k1b_latent<<<64, 256, 0, stream>>>(SVb, W23T, b2, b3, eps, fc1T, fc1_b,
                                     out_mu, out_lv, hbufF);
  k2_decoder<<<dim3(32, 21), 256, 0, stream>>>(hbufF, WF2g, fc2_b, recon);
}